// Round 2
// baseline (115.015 us; speedup 1.0000x reference)
//
#include <hip/hip_runtime.h>
#include <float.h>

// knnFlow: pc1 [B,3,N1] f32, pc2 [B,3,N2] f32 -> flow [B,3,N1] f32
// Must bit-replicate the reference's f32 Gram expansion:
//   sq = (x*x + y*y) + z*z                      (plain rounded ops, no FMA)
//   gram = fma(z1,z2, fma(y1,y2, rnd(x1*x2)))   (einsum/BLAS K=3 FMA chain)
//   d2 = (sq1 + sq2) - 2*gram                   (left-to-right, 2*g exact)
// argmin first-occurrence (strict <, ascending j / ascending split).

#define BATCH 8
#define NPTS1 8192
#define NPTS2 8192
#define NSPLIT 8              // candidate-axis splits
#define TILE   (NPTS2/NSPLIT) // 1024 candidates per split, staged in LDS
#define QPT    4              // queries per thread in partial kernel
#define BLK    256

// ---------------- kernel 1: partial argmin over one candidate split ----------
__global__ __launch_bounds__(BLK) void knn_partial(const float* __restrict__ pc1,
                                                   const float* __restrict__ pc2,
                                                   uint2* __restrict__ part) {
#pragma clang fp contract(off)
    __shared__ float4 tile[TILE];   // (x2, y2, z2, sq2) -> 1 ds_read_b128 broadcast
    const int t    = threadIdx.x;
    const int qblk = blockIdx.x;            // 0..7
    const int s    = blockIdx.y;            // 0..NSPLIT-1
    const int b    = blockIdx.z;            // 0..BATCH-1
    const int j0   = s * TILE;

    const float* p2b = pc2 + (size_t)b * 3 * NPTS2;
    const float* p1b = pc1 + (size_t)b * 3 * NPTS1;

    // stage candidate tile; sq2 replicated: (xx+yy)+zz, squares rounded, no FMA
    for (int j = t; j < TILE; j += BLK) {
        const float x = p2b[0 * NPTS2 + j0 + j];
        const float y = p2b[1 * NPTS2 + j0 + j];
        const float z = p2b[2 * NPTS2 + j0 + j];
        const float xx = x * x;
        const float yy = y * y;
        const float zz = z * z;
        const float sq = (xx + yy) + zz;
        tile[j] = make_float4(x, y, z, sq);
    }
    __syncthreads();

    const int qbase = qblk * (BLK * QPT);
    float x1[QPT], y1[QPT], z1[QPT], sq1[QPT], best[QPT];
    int   bidx[QPT];
    #pragma unroll
    for (int i = 0; i < QPT; ++i) {
        const int q = qbase + t + i * BLK;
        x1[i] = p1b[0 * NPTS1 + q];
        y1[i] = p1b[1 * NPTS1 + q];
        z1[i] = p1b[2 * NPTS1 + q];
        const float xx = x1[i] * x1[i];
        const float yy = y1[i] * y1[i];
        const float zz = z1[i] * z1[i];
        sq1[i] = (xx + yy) + zz;
        best[i] = FLT_MAX;
        bidx[i] = 0;
    }

    #pragma unroll 4
    for (int j = 0; j < TILE; ++j) {
        const float4 c = tile[j];   // wave-uniform address -> broadcast, conflict-free
        #pragma unroll
        for (int i = 0; i < QPT; ++i) {
            const float t0 = x1[i] * c.x;            // rounded mul (contract off)
            const float t1 = fmaf(y1[i], c.y, t0);   // explicit FMA chain
            const float t2 = fmaf(z1[i], c.z, t1);
            const float ss = sq1[i] + c.w;           // (sq1 + sq2), rounded
            const float d2 = ss - 2.0f * t2;         // 2*g exact; sub rounded, not fused
            const bool  lt = d2 < best[i];           // strict <, ascending j
            best[i] = lt ? d2 : best[i];
            bidx[i] = lt ? j  : bidx[i];
        }
    }

    // partial layout [NSPLIT][BATCH*N1] so writes are coalesced
    #pragma unroll
    for (int i = 0; i < QPT; ++i) {
        const int q = qbase + t + i * BLK;
        part[(size_t)s * (BATCH * NPTS1) + (size_t)b * NPTS1 + q] =
            make_uint2(__float_as_uint(best[i]), (unsigned)(j0 + bidx[i]));
    }
}

// ---------------- kernel 2: reduce splits + gather nn + write flow -----------
__global__ __launch_bounds__(BLK) void knn_reduce(const float* __restrict__ pc1,
                                                  const float* __restrict__ pc2,
                                                  const uint2* __restrict__ part,
                                                  float* __restrict__ flow) {
#pragma clang fp contract(off)
    const int g = blockIdx.x * BLK + threadIdx.x;  // 0..BATCH*N1-1
    if (g >= BATCH * NPTS1) return;

    float    best = FLT_MAX;
    unsigned bi   = 0;
    #pragma unroll
    for (int s = 0; s < NSPLIT; ++s) {             // ascending split order, strict <
        const uint2 p = part[(size_t)s * (BATCH * NPTS1) + g];
        const float d = __uint_as_float(p.x);
        if (d < best) { best = d; bi = p.y; }
    }

    const int b = g / NPTS1;
    const int q = g - b * NPTS1;
    const float* p1b = pc1 + (size_t)b * 3 * NPTS1;
    const float* p2b = pc2 + (size_t)b * 3 * NPTS2;
    float* fo = flow + (size_t)b * 3 * NPTS1;
    fo[0 * NPTS1 + q] = p2b[0 * NPTS2 + bi] - p1b[0 * NPTS1 + q];
    fo[1 * NPTS1 + q] = p2b[1 * NPTS2 + bi] - p1b[1 * NPTS1 + q];
    fo[2 * NPTS1 + q] = p2b[2 * NPTS2 + bi] - p1b[2 * NPTS1 + q];
}

// ---------------- fallback: monolithic (no workspace needed) -----------------
__global__ __launch_bounds__(BLK) void knn_mono(const float* __restrict__ pc1,
                                                const float* __restrict__ pc2,
                                                float* __restrict__ flow) {
#pragma clang fp contract(off)
    __shared__ float4 tile[TILE];
    const int t = threadIdx.x;
    const int g = blockIdx.x * BLK + t;   // query id, 0..BATCH*N1-1
    const int b = g / NPTS1;
    const int q = g - b * NPTS1;
    const float* p1b = pc1 + (size_t)b * 3 * NPTS1;
    const float* p2b = pc2 + (size_t)b * 3 * NPTS2;

    const float x1 = p1b[0 * NPTS1 + q];
    const float y1 = p1b[1 * NPTS1 + q];
    const float z1 = p1b[2 * NPTS1 + q];
    const float sq1 = (x1 * x1 + y1 * y1) + z1 * z1;
    float best = FLT_MAX;
    int   bi   = 0;

    for (int s = 0; s < NSPLIT; ++s) {
        __syncthreads();
        for (int j = t; j < TILE; j += BLK) {
            const int jj = s * TILE + j;
            const float x = p2b[jj];
            const float y = p2b[NPTS2 + jj];
            const float z = p2b[2 * NPTS2 + jj];
            const float sq = (x * x + y * y) + z * z;
            tile[j] = make_float4(x, y, z, sq);
        }
        __syncthreads();
        #pragma unroll 4
        for (int j = 0; j < TILE; ++j) {
            const float4 c = tile[j];
            const float t0 = x1 * c.x;
            const float t1 = fmaf(y1, c.y, t0);
            const float t2 = fmaf(z1, c.z, t1);
            const float ss = sq1 + c.w;
            const float d2 = ss - 2.0f * t2;
            const bool  lt = d2 < best;
            best = lt ? d2 : best;
            bi   = lt ? s * TILE + j : bi;
        }
    }
    float* fo = flow + (size_t)b * 3 * NPTS1;
    fo[0 * NPTS1 + q] = p2b[0 * NPTS2 + bi] - x1;
    fo[1 * NPTS1 + q] = p2b[1 * NPTS2 + bi] - y1;
    fo[2 * NPTS1 + q] = p2b[2 * NPTS2 + bi] - z1;
}

extern "C" void kernel_launch(void* const* d_in, const int* in_sizes, int n_in,
                              void* d_out, int out_size, void* d_ws, size_t ws_size,
                              hipStream_t stream) {
    const float* pc1 = (const float*)d_in[0];
    const float* pc2 = (const float*)d_in[1];
    float* flow = (float*)d_out;

    const size_t part_bytes = (size_t)NSPLIT * BATCH * NPTS1 * sizeof(uint2); // 4 MiB

    if (ws_size >= part_bytes) {
        uint2* part = (uint2*)d_ws;
        dim3 grid1(NPTS1 / (BLK * QPT), NSPLIT, BATCH);   // (8, 8, 8) = 512 blocks
        knn_partial<<<grid1, BLK, 0, stream>>>(pc1, pc2, part);
        const int nq = BATCH * NPTS1;
        knn_reduce<<<(nq + BLK - 1) / BLK, BLK, 0, stream>>>(pc1, pc2, part, flow);
    } else {
        const int nq = BATCH * NPTS1;
        knn_mono<<<(nq + BLK - 1) / BLK, BLK, 0, stream>>>(pc1, pc2, flow);
    }
}

// Round 3
// 104.196 us; speedup vs baseline: 1.1038x; 1.1038x over previous
//
#include <hip/hip_runtime.h>
#include <float.h>

// knnFlow: pc1 [B,3,N1] f32, pc2 [B,3,N2] f32 -> flow [B,3,N1] f32
// Bit-replicates the reference's f32 Gram expansion (verified absmax 0.0 in R2):
//   sq = (x*x + y*y) + z*z                      (plain rounded ops, no FMA)
//   gram = fma(z1,z2, fma(y1,y2, rnd(x1*x2)))   (einsum/BLAS K=3 FMA chain)
//   d2 = (sq1 + sq2) - 2*gram
//     == fmaf(gram, -2.0f, sq1+sq2)  BIT-EXACT: 2*gram is an exponent shift
//        (exact), so the fused single rounding equals rnd(ss - rnd(2*gram)).
// argmin first-occurrence (strict <, ascending j / ascending split).

#define BATCH 8
#define NPTS1 8192
#define NPTS2 8192
#define QPT    4              // queries per thread in partial kernel
#define BLK    256

// ---------------- kernel 1: partial argmin over one candidate split ----------
// NS = number of candidate-axis splits; TILE = NPTS2/NS candidates in LDS.
template <int NS>
__global__ __launch_bounds__(BLK) void knn_partial(const float* __restrict__ pc1,
                                                   const float* __restrict__ pc2,
                                                   uint2* __restrict__ part) {
#pragma clang fp contract(off)
    constexpr int TILE = NPTS2 / NS;
    __shared__ float4 tile[TILE];   // (x2, y2, z2, sq2) -> 1 ds_read_b128 broadcast
    const int t    = threadIdx.x;
    const int qblk = blockIdx.x;            // 0..NPTS1/(BLK*QPT)-1
    const int s    = blockIdx.y;            // 0..NS-1
    const int b    = blockIdx.z;            // 0..BATCH-1
    const int j0   = s * TILE;

    const float* p2b = pc2 + (size_t)b * 3 * NPTS2;
    const float* p1b = pc1 + (size_t)b * 3 * NPTS1;

    // stage candidate tile; sq2 replicated: (xx+yy)+zz, squares rounded, no FMA
    for (int j = t; j < TILE; j += BLK) {
        const float x = p2b[0 * NPTS2 + j0 + j];
        const float y = p2b[1 * NPTS2 + j0 + j];
        const float z = p2b[2 * NPTS2 + j0 + j];
        const float xx = x * x;
        const float yy = y * y;
        const float zz = z * z;
        const float sq = (xx + yy) + zz;
        tile[j] = make_float4(x, y, z, sq);
    }
    __syncthreads();

    const int qbase = qblk * (BLK * QPT);
    float x1[QPT], y1[QPT], z1[QPT], sq1[QPT], best[QPT];
    int   bidx[QPT];
    #pragma unroll
    for (int i = 0; i < QPT; ++i) {
        const int q = qbase + t + i * BLK;
        x1[i] = p1b[0 * NPTS1 + q];
        y1[i] = p1b[1 * NPTS1 + q];
        z1[i] = p1b[2 * NPTS1 + q];
        const float xx = x1[i] * x1[i];
        const float yy = y1[i] * y1[i];
        const float zz = z1[i] * z1[i];
        sq1[i] = (xx + yy) + zz;
        best[i] = FLT_MAX;
        bidx[i] = 0;
    }

    #pragma unroll 4
    for (int j = 0; j < TILE; ++j) {
        const float4 c = tile[j];   // wave-uniform address -> broadcast, conflict-free
        #pragma unroll
        for (int i = 0; i < QPT; ++i) {
            const float t0 = x1[i] * c.x;            // rounded mul (contract off)
            const float t1 = fmaf(y1[i], c.y, t0);   // explicit FMA chain
            const float t2 = fmaf(z1[i], c.z, t1);
            const float ss = sq1[i] + c.w;           // (sq1 + sq2), rounded
            const float d2 = fmaf(t2, -2.0f, ss);    // == ss - 2*t2 bit-exactly
            const bool  lt = d2 < best[i];           // strict <, ascending j
            best[i] = lt ? d2 : best[i];
            bidx[i] = lt ? j  : bidx[i];
        }
    }

    // partial layout [NS][BATCH*N1] so writes are coalesced
    #pragma unroll
    for (int i = 0; i < QPT; ++i) {
        const int q = qbase + t + i * BLK;
        part[(size_t)s * (BATCH * NPTS1) + (size_t)b * NPTS1 + q] =
            make_uint2(__float_as_uint(best[i]), (unsigned)(j0 + bidx[i]));
    }
}

// ---------------- kernel 2: reduce splits + gather nn + write flow -----------
template <int NS>
__global__ __launch_bounds__(BLK) void knn_reduce(const float* __restrict__ pc1,
                                                  const float* __restrict__ pc2,
                                                  const uint2* __restrict__ part,
                                                  float* __restrict__ flow) {
#pragma clang fp contract(off)
    const int g = blockIdx.x * BLK + threadIdx.x;  // 0..BATCH*N1-1
    if (g >= BATCH * NPTS1) return;

    float    best = FLT_MAX;
    unsigned bi   = 0;
    #pragma unroll
    for (int s = 0; s < NS; ++s) {                 // ascending split order, strict <
        const uint2 p = part[(size_t)s * (BATCH * NPTS1) + g];
        const float d = __uint_as_float(p.x);
        if (d < best) { best = d; bi = p.y; }
    }

    const int b = g / NPTS1;
    const int q = g - b * NPTS1;
    const float* p1b = pc1 + (size_t)b * 3 * NPTS1;
    const float* p2b = pc2 + (size_t)b * 3 * NPTS2;
    float* fo = flow + (size_t)b * 3 * NPTS1;
    fo[0 * NPTS1 + q] = p2b[0 * NPTS2 + bi] - p1b[0 * NPTS1 + q];
    fo[1 * NPTS1 + q] = p2b[1 * NPTS2 + bi] - p1b[1 * NPTS1 + q];
    fo[2 * NPTS1 + q] = p2b[2 * NPTS2 + bi] - p1b[2 * NPTS1 + q];
}

// ---------------- fallback: monolithic (no workspace needed) -----------------
__global__ __launch_bounds__(BLK) void knn_mono(const float* __restrict__ pc1,
                                                const float* __restrict__ pc2,
                                                float* __restrict__ flow) {
#pragma clang fp contract(off)
    constexpr int TILE = 1024;
    __shared__ float4 tile[TILE];
    const int t = threadIdx.x;
    const int g = blockIdx.x * BLK + t;   // query id, 0..BATCH*N1-1
    const int b = g / NPTS1;
    const int q = g - b * NPTS1;
    const float* p1b = pc1 + (size_t)b * 3 * NPTS1;
    const float* p2b = pc2 + (size_t)b * 3 * NPTS2;

    const float x1 = p1b[0 * NPTS1 + q];
    const float y1 = p1b[1 * NPTS1 + q];
    const float z1 = p1b[2 * NPTS1 + q];
    const float sq1 = (x1 * x1 + y1 * y1) + z1 * z1;
    float best = FLT_MAX;
    int   bi   = 0;

    for (int s = 0; s < NPTS2 / TILE; ++s) {
        __syncthreads();
        for (int j = t; j < TILE; j += BLK) {
            const int jj = s * TILE + j;
            const float x = p2b[jj];
            const float y = p2b[NPTS2 + jj];
            const float z = p2b[2 * NPTS2 + jj];
            const float sq = (x * x + y * y) + z * z;
            tile[j] = make_float4(x, y, z, sq);
        }
        __syncthreads();
        #pragma unroll 4
        for (int j = 0; j < TILE; ++j) {
            const float4 c = tile[j];
            const float t0 = x1 * c.x;
            const float t1 = fmaf(y1, c.y, t0);
            const float t2 = fmaf(z1, c.z, t1);
            const float ss = sq1 + c.w;
            const float d2 = fmaf(t2, -2.0f, ss);
            const bool  lt = d2 < best;
            best = lt ? d2 : best;
            bi   = lt ? s * TILE + j : bi;
        }
    }
    float* fo = flow + (size_t)b * 3 * NPTS1;
    fo[0 * NPTS1 + q] = p2b[0 * NPTS2 + bi] - x1;
    fo[1 * NPTS1 + q] = p2b[1 * NPTS2 + bi] - y1;
    fo[2 * NPTS1 + q] = p2b[2 * NPTS2 + bi] - z1;
}

extern "C" void kernel_launch(void* const* d_in, const int* in_sizes, int n_in,
                              void* d_out, int out_size, void* d_ws, size_t ws_size,
                              hipStream_t stream) {
    const float* pc1 = (const float*)d_in[0];
    const float* pc2 = (const float*)d_in[1];
    float* flow = (float*)d_out;

    const int nq = BATCH * NPTS1;
    auto part_bytes = [](int ns) { return (size_t)ns * BATCH * NPTS1 * sizeof(uint2); };

    if (ws_size >= part_bytes(32)) {
        // 8 qblocks x 32 splits x 8 batches = 2048 blocks = 8 blocks/CU
        // = 32 waves/CU (100% occupancy at VGPR<=64, LDS 4KB/block)
        uint2* part = (uint2*)d_ws;
        dim3 grid1(NPTS1 / (BLK * QPT), 32, BATCH);
        knn_partial<32><<<grid1, BLK, 0, stream>>>(pc1, pc2, part);
        knn_reduce<32><<<(nq + BLK - 1) / BLK, BLK, 0, stream>>>(pc1, pc2, part, flow);
    } else if (ws_size >= part_bytes(16)) {
        uint2* part = (uint2*)d_ws;
        dim3 grid1(NPTS1 / (BLK * QPT), 16, BATCH);
        knn_partial<16><<<grid1, BLK, 0, stream>>>(pc1, pc2, part);
        knn_reduce<16><<<(nq + BLK - 1) / BLK, BLK, 0, stream>>>(pc1, pc2, part, flow);
    } else if (ws_size >= part_bytes(8)) {
        uint2* part = (uint2*)d_ws;
        dim3 grid1(NPTS1 / (BLK * QPT), 8, BATCH);
        knn_partial<8><<<grid1, BLK, 0, stream>>>(pc1, pc2, part);
        knn_reduce<8><<<(nq + BLK - 1) / BLK, BLK, 0, stream>>>(pc1, pc2, part, flow);
    } else {
        knn_mono<<<(nq + BLK - 1) / BLK, BLK, 0, stream>>>(pc1, pc2, flow);
    }
}